// Round 1
// baseline (372.233 us; speedup 1.0000x reference)
//
#include <hip/hip_runtime.h>
#include <math.h>

#define B_ 16
#define SEQ_ 8192
#define C_ 192
#define H_ 16
#define OV_ 4
#define G_ 6
#define K_ 1024
#define D_ 8
#define DG_ 2048
#define W_ 512
#define T_ 128
#define TT 4
#define OUT_ELEMS (B_ * SEQ_ * C_)   // 25165824

// workspace layout:
//   pd_perm : float [G*DG*D]  = 98304 floats   @ byte 0
//   pu_perm : float [G*D*DG]  = 98304 floats   @ byte 393216
//   cbn_d   : double[G*K*D]   = 49152 doubles  @ byte 786432
// total = 1179648 bytes

// d' = h*128 + ul  <->  group-local d = ul*16 + h,  u = g*128 + ul = o*192 + c
// NOTE: o*192 + c == u, so z addresses are LINEAR in u: no o/c split needed.

__global__ __launch_bounds__(256) void vq_prep(
    const float* __restrict__ pd, const float* __restrict__ pu,
    const float* __restrict__ cb,
    float* __restrict__ pd_p, float* __restrict__ pu_p,
    double* __restrict__ cbn, float* __restrict__ loss_slots)
{
  int i = blockIdx.x * 256 + threadIdx.x;
  if (i < 98304) {                       // pd_perm[g][d'][e]
    int e = i & 7, dp = (i >> 3) & 2047, g = i >> 14;
    int h = dp >> 7, ul = dp & 127, d = (ul << 4) + h;
    pd_p[i] = pd[(g << 14) + (d << 3) + e];
  } else if (i < 196608) {               // pu_perm[g][e][d']
    int i2 = i - 98304;
    int dp = i2 & 2047, e = (i2 >> 11) & 7, g = i2 >> 14;
    int h = dp >> 7, ul = dp & 127, d = (ul << 4) + h;
    pu_p[i2] = pu[(g << 14) + (e << 11) + d];
  } else if (i < 202752) {               // normalized codebooks, fp64
    int j = i - 196608;                  // j = g*1024 + k
    const float* row = cb + (j << 3);
    double ss = 0.0;
    #pragma unroll
    for (int e = 0; e < 8; ++e) { double x = (double)row[e]; ss += x * x; }
    double inv = 1.0 / fmax(sqrt(ss), 1e-12);
    #pragma unroll
    for (int e = 0; e < 8; ++e) cbn[(j << 3) + e] = (double)row[e] * inv;
  } else if (i < 202784) {               // zero the 32 loss accumulators
    loss_slots[i - 202752] = 0.0f;
  }
}

__global__ __launch_bounds__(256, 6) void vq_main(
    const float* __restrict__ z, const float* __restrict__ cb,
    const float* __restrict__ pd_p, const float* __restrict__ pu_p,
    const double* __restrict__ cbn,
    float* __restrict__ out, float* __restrict__ loss_slots)
{
  __shared__ double ze_d[TT * 8];
  __shared__ float  zq_s[TT * 8];
  __shared__ double wr_s[4][TT];
  __shared__ int    wr_k[4][TT];
  __shared__ float  lossv[TT];

  const int tid  = threadIdx.x;
  const int lane = tid & 63;
  const int wv   = tid >> 6;    // wave id == local frame t (TT==4 waves)
  const int tc   = blockIdx.x;  // 0..31 (chunk of TT=4 grouped frames)
  const int g    = blockIdx.y;  // 0..5
  const int b    = blockIdx.z;  // 0..15

  const float* zb = z + (size_t)b * (SEQ_ * C_);

  // ---------- phase 1: z_e for frame t=wv, direct-from-global, fp64 accum ----
  // wave handles all dp; lane covers dp = h*128 + {2*lane, 2*lane+1}
  {
    const int wbase = (tc * TT + wv) * OV_;
    // z addr for (h, ul): zb + (h*512 + wbase)*192 + g*128 + ul   (linear in ul)
    const float* zcol = zb + (size_t)wbase * 192 + (g << 7) + (lane << 1);
    const float4* pdg = (const float4*)(pd_p + ((g << 11) << 3)); // 2 float4 per dp row

    double acc[8];
    #pragma unroll
    for (int e = 0; e < 8; ++e) acc[e] = 0.0;

    #pragma unroll 2
    for (int h = 0; h < 16; ++h) {
      const float2 zv = *(const float2*)(zcol + h * (512 * 192));
      const int dp = (h << 7) + (lane << 1);
      const float4 p00 = pdg[(dp << 1) + 0];
      const float4 p01 = pdg[(dp << 1) + 1];
      const float4 p10 = pdg[(dp << 1) + 2];
      const float4 p11 = pdg[(dp << 1) + 3];
      const double z0 = (double)zv.x, z1 = (double)zv.y;
      acc[0] = fma(z0, (double)p00.x, acc[0]);
      acc[1] = fma(z0, (double)p00.y, acc[1]);
      acc[2] = fma(z0, (double)p00.z, acc[2]);
      acc[3] = fma(z0, (double)p00.w, acc[3]);
      acc[4] = fma(z0, (double)p01.x, acc[4]);
      acc[5] = fma(z0, (double)p01.y, acc[5]);
      acc[6] = fma(z0, (double)p01.z, acc[6]);
      acc[7] = fma(z0, (double)p01.w, acc[7]);
      acc[0] = fma(z1, (double)p10.x, acc[0]);
      acc[1] = fma(z1, (double)p10.y, acc[1]);
      acc[2] = fma(z1, (double)p10.z, acc[2]);
      acc[3] = fma(z1, (double)p10.w, acc[3]);
      acc[4] = fma(z1, (double)p11.x, acc[4]);
      acc[5] = fma(z1, (double)p11.y, acc[5]);
      acc[6] = fma(z1, (double)p11.z, acc[6]);
      acc[7] = fma(z1, (double)p11.w, acc[7]);
    }

    // in-wave butterfly reduction of the 8 fp64 partials
    #pragma unroll
    for (int m = 32; m >= 1; m >>= 1) {
      #pragma unroll
      for (int e = 0; e < 8; ++e) acc[e] += __shfl_xor(acc[e], m);
    }
    if (lane == 0) {
      #pragma unroll
      for (int e = 0; e < 8; ++e) ze_d[wv * 8 + e] = acc[e];
    }
  }
  __syncthreads();

  // ---------- phase 2: argmax over 1024 codes (fp64 sim, first-max tie-break) ----------
  double cd[4][8];
  #pragma unroll
  for (int q = 0; q < 4; ++q) {
    const double* cr = cbn + (((g << 10) + (q << 8) + tid) << 3);
    #pragma unroll
    for (int e = 0; e < 8; ++e) cd[q][e] = cr[e];
  }
  double bs[TT]; int bk[TT];
  #pragma unroll
  for (int t = 0; t < TT; ++t) {
    double zr[8];
    #pragma unroll
    for (int e = 0; e < 8; ++e) zr[e] = ze_d[t * 8 + e];
    bs[t] = -1.0e300; bk[t] = 0x7fffffff;
    #pragma unroll
    for (int q = 0; q < 4; ++q) {
      double s = 0.0;
      #pragma unroll
      for (int e = 0; e < 8; ++e) s = fma(zr[e], cd[q][e], s);
      int k = (q << 8) + tid;          // ascending within thread -> strict > keeps min k
      if (s > bs[t]) { bs[t] = s; bk[t] = k; }
    }
  }
  #pragma unroll
  for (int m = 32; m >= 1; m >>= 1) {
    #pragma unroll
    for (int t = 0; t < TT; ++t) {
      double os = __shfl_xor(bs[t], m);
      int    ok = __shfl_xor(bk[t], m);
      if (os > bs[t] || (os == bs[t] && ok < bk[t])) { bs[t] = os; bk[t] = ok; }
    }
  }
  int wv4 = tid >> 6;
  if ((tid & 63) == 0) {
    #pragma unroll
    for (int t = 0; t < TT; ++t) { wr_s[wv4][t] = bs[t]; wr_k[wv4][t] = bk[t]; }
  }
  __syncthreads();
  if (tid < TT) {
    int t = tid;
    double s0 = wr_s[0][t]; int k0 = wr_k[0][t];
    #pragma unroll
    for (int w2 = 1; w2 < 4; ++w2) {
      double s1 = wr_s[w2][t]; int k1 = wr_k[w2][t];
      if (s1 > s0 || (s1 == s0 && k1 < k0)) { s0 = s1; k0 = k1; }
    }
    const float* crow = cb + (((g << 10) + k0) << 3);   // RAW codebook row
    double l = 0.0;
    #pragma unroll
    for (int e = 0; e < 8; ++e) {
      float qv = crow[e];
      zq_s[t * 8 + e] = qv;
      double dd = ze_d[t * 8 + e] - (double)qv;
      l = fma(dd, dd, l);
    }
    lossv[t] = (float)l;
  }
  __syncthreads();
  if (tid == 0) {
    float l = (lossv[0] + lossv[1] + lossv[2] + lossv[3]) * (1.0f / (T_ * D_ * G_));
    atomicAdd(loss_slots + b, l);        // commitment
    atomicAdd(loss_slots + 16 + b, l);   // codebook loss (numerically identical)
  }

  // ---------- phase 3: out = z_q @ proj_up, scatter-coalesced ----------
  float zqr[TT][8];
  #pragma unroll
  for (int t = 0; t < TT; ++t)
    #pragma unroll
    for (int e = 0; e < 8; ++e) zqr[t][e] = zq_s[t * 8 + e];

  #pragma unroll
  for (int j = 0; j < 8; ++j) {
    int dp = j * 256 + tid;
    int h = dp >> 7, ul = dp & 127;
    int u = (g << 7) + ul;
    int o = (u * 683) >> 17;
    int c = u - o * 192;
    float pv[8];
    #pragma unroll
    for (int e = 0; e < 8; ++e) pv[e] = pu_p[(g << 14) + (e << 11) + dp];
    size_t base = ((size_t)(b * SEQ_) + h * 512 + tc * (TT * OV_) + o) * 192 + c;
    #pragma unroll
    for (int t = 0; t < TT; ++t) {
      float v = 0.f;
      #pragma unroll
      for (int e = 0; e < 8; ++e) v = fmaf(zqr[t][e], pv[e], v);
      out[base + (size_t)(t * OV_ * 192)] = v;
    }
  }
}

extern "C" void kernel_launch(void* const* d_in, const int* in_sizes, int n_in,
                              void* d_out, int out_size, void* d_ws, size_t ws_size,
                              hipStream_t stream)
{
  const float* z  = (const float*)d_in[0];   // (B, SEQ, C)
  const float* pd = (const float*)d_in[1];   // (G, DG, D)
  const float* pu = (const float*)d_in[2];   // (G, D, DG)
  const float* cb = (const float*)d_in[3];   // (G, K, D)
  float* out = (float*)d_out;
  float* loss_slots = out + OUT_ELEMS;       // 16 commitment + 16 codebook

  float*  pd_p = (float*)d_ws;
  float*  pu_p = pd_p + 98304;
  double* cbn  = (double*)(pu_p + 98304);

  vq_prep<<<793, 256, 0, stream>>>(pd, pu, cb, pd_p, pu_p, cbn, loss_slots);
  dim3 grid(T_ / TT, G_, B_);
  vq_main<<<grid, 256, 0, stream>>>(z, cb, pd_p, pu_p, cbn, out, loss_slots);
}

// Round 2
// 342.543 us; speedup vs baseline: 1.0867x; 1.0867x over previous
//
#include <hip/hip_runtime.h>
#include <math.h>

#define B_ 16
#define SEQ_ 8192
#define C_ 192
#define H_ 16
#define OV_ 4
#define G_ 6
#define K_ 1024
#define D_ 8
#define DG_ 2048
#define W_ 512
#define T_ 128
#define TT 4
#define OUT_ELEMS (B_ * SEQ_ * C_)   // 25165824

// workspace layout:
//   pd_perm : float [G*DG*D]  = 98304 floats   @ byte 0
//   pu_perm : float [G*D*DG]  = 98304 floats   @ byte 393216
//   cbn_d   : double[G*K*D]   = 49152 doubles  @ byte 786432
// total = 1179648 bytes

// d' = h*128 + ul  <->  group-local d = ul*16 + h,  u = g*128 + ul = o*192 + c
// o*192 + c == u, so z addresses are LINEAR in u (no o/c split needed):
//   z[t][dp] = zb[(h*512 + (tc*4+t)*4)*192 + g*128 + ul]

__global__ __launch_bounds__(256) void vq_prep(
    const float* __restrict__ pd, const float* __restrict__ pu,
    const float* __restrict__ cb,
    float* __restrict__ pd_p, float* __restrict__ pu_p,
    double* __restrict__ cbn, float* __restrict__ loss_slots)
{
  int i = blockIdx.x * 256 + threadIdx.x;
  if (i < 98304) {                       // pd_perm[g][d'][e]
    int e = i & 7, dp = (i >> 3) & 2047, g = i >> 14;
    int h = dp >> 7, ul = dp & 127, d = (ul << 4) + h;
    pd_p[i] = pd[(g << 14) + (d << 3) + e];
  } else if (i < 196608) {               // pu_perm[g][e][d']
    int i2 = i - 98304;
    int dp = i2 & 2047, e = (i2 >> 11) & 7, g = i2 >> 14;
    int h = dp >> 7, ul = dp & 127, d = (ul << 4) + h;
    pu_p[i2] = pu[(g << 14) + (e << 11) + d];
  } else if (i < 202752) {               // normalized codebooks, fp64
    int j = i - 196608;                  // j = g*1024 + k
    const float* row = cb + (j << 3);
    double ss = 0.0;
    #pragma unroll
    for (int e = 0; e < 8; ++e) { double x = (double)row[e]; ss += x * x; }
    double inv = 1.0 / fmax(sqrt(ss), 1e-12);
    #pragma unroll
    for (int e = 0; e < 8; ++e) cbn[(j << 3) + e] = (double)row[e] * inv;
  } else if (i < 202784) {               // zero the 32 loss accumulators
    loss_slots[i - 202752] = 0.0f;
  }
}

__global__ __launch_bounds__(256, 6) void vq_main(
    const float* __restrict__ z, const float* __restrict__ cb,
    const float* __restrict__ pd_p, const float* __restrict__ pu_p,
    const double* __restrict__ cbn,
    float* __restrict__ out, float* __restrict__ loss_slots)
{
  __shared__ double part_d[16 * 128];   // 16 KB reduction buffer
  __shared__ double ze_d[TT * 8];
  __shared__ float  zq_s[TT * 8];
  __shared__ double wr_s[4][TT];
  __shared__ int    wr_k[4][TT];
  __shared__ float  lossv[TT];

  const int tid = threadIdx.x;
  const int tl  = tid & 127;    // index within e-half
  const int eh  = tid >> 7;     // which half of e (0: e0..3, 1: e4..7)
  const int tc  = blockIdx.x;   // 0..31 (chunk of TT=4 grouped frames)
  const int g   = blockIdx.y;   // 0..5
  const int b   = blockIdx.z;   // 0..15

  const float* zb = z + (size_t)b * (SEQ_ * C_);

  // ---------- phase 1: z_e partials, z direct-from-global, fp64 accum -------
  // thread owns dp pairs {i*256 + 2*tl, +1} for i in [0,8), e-range eh*4..+3.
  // pd read ONCE per block (each 16B half-row by exactly one thread).
  double acc[TT][4];
  #pragma unroll
  for (int t = 0; t < TT; ++t)
    #pragma unroll
    for (int j = 0; j < 4; ++j) acc[t][j] = 0.0;

  {
    const int hofs = tl >> 6;            // dp0>>7 parity
    const int ul2  = (tl & 63) << 1;
    const float* zbase = zb + (size_t)(tc * (TT * OV_)) * 192 + (g << 7) + ul2;
    const float* pdg = pd_p + ((g << 11) << 3) + (eh << 2);

    #pragma unroll 2
    for (int i = 0; i < 8; ++i) {
      const int h = (i << 1) + hofs;
      const float* zp = zbase + (size_t)h * (512 * 192);
      float2 zv[TT];
      #pragma unroll
      for (int t = 0; t < TT; ++t)
        zv[t] = *(const float2*)(zp + t * (OV_ * 192));
      const int dp0 = (i << 8) + (tl << 1);
      const float4 pa = *(const float4*)(pdg + (dp0 << 3));        // row dp0, e-half
      const float4 pb = *(const float4*)(pdg + ((dp0 + 1) << 3));  // row dp0+1, e-half
      #pragma unroll
      for (int t = 0; t < TT; ++t) {
        const double z0 = (double)zv[t].x, z1 = (double)zv[t].y;
        acc[t][0] = fma(z0, (double)pa.x, acc[t][0]);
        acc[t][1] = fma(z0, (double)pa.y, acc[t][1]);
        acc[t][2] = fma(z0, (double)pa.z, acc[t][2]);
        acc[t][3] = fma(z0, (double)pa.w, acc[t][3]);
        acc[t][0] = fma(z1, (double)pb.x, acc[t][0]);
        acc[t][1] = fma(z1, (double)pb.y, acc[t][1]);
        acc[t][2] = fma(z1, (double)pb.z, acc[t][2]);
        acc[t][3] = fma(z1, (double)pb.w, acc[t][3]);
      }
    }
  }

  // ---------- phase 1.5: block reduction, 2 rounds x 16 (t,e)-slots, fp64 ---
  // slot = tl2*8 + eh*4 + j  (tl2 = t within round pair); 128 partials/slot.
  #pragma unroll
  for (int r = 0; r < 2; ++r) {
    __syncthreads();
    #pragma unroll
    for (int tl2 = 0; tl2 < 2; ++tl2)
      #pragma unroll
      for (int j = 0; j < 4; ++j)
        part_d[(((tl2 << 3) + (eh << 2) + j) << 7) + tl] = acc[(r << 1) + tl2][j];
    __syncthreads();
    const int slot = tid >> 4, jj = tid & 15;
    double partial = 0.0;
    #pragma unroll
    for (int s = 0; s < 8; ++s)
      partial += part_d[(slot << 7) + (s << 4) + jj];
    partial += __shfl_down(partial, 8, 16);
    partial += __shfl_down(partial, 4, 16);
    partial += __shfl_down(partial, 2, 16);
    partial += __shfl_down(partial, 1, 16);
    if (jj == 0) ze_d[(r << 4) + slot] = partial;   // kk = t*8+e = r*16 + slot
  }
  __syncthreads();

  // ---------- phase 2: argmax over 1024 codes (fp64 sim, first-max tie-break)
  // codebook rows processed in pairs to halve live registers.
  double bs[TT]; int bk[TT];
  #pragma unroll
  for (int t = 0; t < TT; ++t) { bs[t] = -1.0e300; bk[t] = 0x7fffffff; }

  #pragma unroll
  for (int qp = 0; qp < 2; ++qp) {
    double cd2[2][8];
    #pragma unroll
    for (int qi = 0; qi < 2; ++qi) {
      const double* cr = cbn + (((g << 10) + (((qp << 1) + qi) << 8) + tid) << 3);
      #pragma unroll
      for (int e = 0; e < 8; ++e) cd2[qi][e] = cr[e];
    }
    #pragma unroll
    for (int t = 0; t < TT; ++t) {
      double s0 = 0.0, s1 = 0.0;
      #pragma unroll
      for (int e = 0; e < 8; ++e) {
        const double zr = ze_d[t * 8 + e];
        s0 = fma(zr, cd2[0][e], s0);
        s1 = fma(zr, cd2[1][e], s1);
      }
      const int k0 = ((qp << 1) << 8) + tid;        // ascending k within thread
      const int k1 = (((qp << 1) + 1) << 8) + tid;  // -> strict > keeps min k
      if (s0 > bs[t]) { bs[t] = s0; bk[t] = k0; }
      if (s1 > bs[t]) { bs[t] = s1; bk[t] = k1; }
    }
  }
  #pragma unroll
  for (int m = 32; m >= 1; m >>= 1) {
    #pragma unroll
    for (int t = 0; t < TT; ++t) {
      double os = __shfl_xor(bs[t], m);
      int    ok = __shfl_xor(bk[t], m);
      if (os > bs[t] || (os == bs[t] && ok < bk[t])) { bs[t] = os; bk[t] = ok; }
    }
  }
  const int wv4 = tid >> 6;
  if ((tid & 63) == 0) {
    #pragma unroll
    for (int t = 0; t < TT; ++t) { wr_s[wv4][t] = bs[t]; wr_k[wv4][t] = bk[t]; }
  }
  __syncthreads();
  if (tid < TT) {
    int t = tid;
    double s0 = wr_s[0][t]; int k0 = wr_k[0][t];
    #pragma unroll
    for (int w2 = 1; w2 < 4; ++w2) {
      double s1 = wr_s[w2][t]; int k1 = wr_k[w2][t];
      if (s1 > s0 || (s1 == s0 && k1 < k0)) { s0 = s1; k0 = k1; }
    }
    const float* crow = cb + (((g << 10) + k0) << 3);   // RAW codebook row
    double l = 0.0;
    #pragma unroll
    for (int e = 0; e < 8; ++e) {
      float qv = crow[e];
      zq_s[t * 8 + e] = qv;
      double dd = ze_d[t * 8 + e] - (double)qv;
      l = fma(dd, dd, l);
    }
    lossv[t] = (float)l;
  }
  __syncthreads();
  if (tid == 0) {
    float l = (lossv[0] + lossv[1] + lossv[2] + lossv[3]) * (1.0f / (T_ * D_ * G_));
    atomicAdd(loss_slots + b, l);        // commitment
    atomicAdd(loss_slots + 16 + b, l);   // codebook loss (numerically identical)
  }

  // ---------- phase 3: out = z_q @ proj_up, scatter-coalesced ----------
  float zqr[TT][8];
  #pragma unroll
  for (int t = 0; t < TT; ++t)
    #pragma unroll
    for (int e = 0; e < 8; ++e) zqr[t][e] = zq_s[t * 8 + e];

  #pragma unroll
  for (int j = 0; j < 8; ++j) {
    int dp = j * 256 + tid;
    int h = dp >> 7, ul = dp & 127;
    int u = (g << 7) + ul;
    int o = (u * 683) >> 17;
    int c = u - o * 192;
    float pv[8];
    #pragma unroll
    for (int e = 0; e < 8; ++e) pv[e] = pu_p[(g << 14) + (e << 11) + dp];
    size_t base = ((size_t)(b * SEQ_) + h * 512 + tc * (TT * OV_) + o) * 192 + c;
    #pragma unroll
    for (int t = 0; t < TT; ++t) {
      float v = 0.f;
      #pragma unroll
      for (int e = 0; e < 8; ++e) v = fmaf(zqr[t][e], pv[e], v);
      out[base + (size_t)(t * OV_ * 192)] = v;
    }
  }
}

extern "C" void kernel_launch(void* const* d_in, const int* in_sizes, int n_in,
                              void* d_out, int out_size, void* d_ws, size_t ws_size,
                              hipStream_t stream)
{
  const float* z  = (const float*)d_in[0];   // (B, SEQ, C)
  const float* pd = (const float*)d_in[1];   // (G, DG, D)
  const float* pu = (const float*)d_in[2];   // (G, D, DG)
  const float* cb = (const float*)d_in[3];   // (G, K, D)
  float* out = (float*)d_out;
  float* loss_slots = out + OUT_ELEMS;       // 16 commitment + 16 codebook

  float*  pd_p = (float*)d_ws;
  float*  pu_p = pd_p + 98304;
  double* cbn  = (double*)(pu_p + 98304);

  vq_prep<<<793, 256, 0, stream>>>(pd, pu, cb, pd_p, pu_p, cbn, loss_slots);
  dim3 grid(T_ / TT, G_, B_);
  vq_main<<<grid, 256, 0, stream>>>(z, cb, pd_p, pu_p, cbn, out, loss_slots);
}

// Round 3
// 233.050 us; speedup vs baseline: 1.5972x; 1.4698x over previous
//
#include <hip/hip_runtime.h>
#include <math.h>

#define B_ 16
#define SEQ_ 8192
#define C_ 192
#define H_ 16
#define OV_ 4
#define G_ 6
#define K_ 1024
#define D_ 8
#define DG_ 2048
#define W_ 512
#define T_ 128
#define TT 4
#define OUT_ELEMS (B_ * SEQ_ * C_)   // 25165824

// workspace layout:
//   pd_perm : float [G*DG*D]  = 98304 floats   @ byte 0
//   pu_perm : float [G*D*DG]  = 98304 floats   @ byte 393216
//   cbn_d   : double[G*K*D]   = 49152 doubles  @ byte 786432
// total = 1179648 bytes

// d' = h*128 + ul  <->  group-local d = ul*16 + h,  u = g*128 + ul = o*192 + c
// o*192 + c == u, so z addresses are LINEAR in u (no o/c split needed):
//   z[t][dp] = zb[(h*512 + (tc*4+t)*4)*192 + g*128 + ul]
//
// NOTE: plain __launch_bounds__(256) — the (256,6) min-waves clamp in the
// previous round forced a 40-VGPR allocation for ~60-80 live values ->
// scratch spills -> ~190 MB of extra HBM fetch AND write per dispatch.

__global__ __launch_bounds__(256) void vq_prep(
    const float* __restrict__ pd, const float* __restrict__ pu,
    const float* __restrict__ cb,
    float* __restrict__ pd_p, float* __restrict__ pu_p,
    double* __restrict__ cbn, float* __restrict__ loss_slots)
{
  int i = blockIdx.x * 256 + threadIdx.x;
  if (i < 98304) {                       // pd_perm[g][d'][e]
    int e = i & 7, dp = (i >> 3) & 2047, g = i >> 14;
    int h = dp >> 7, ul = dp & 127, d = (ul << 4) + h;
    pd_p[i] = pd[(g << 14) + (d << 3) + e];
  } else if (i < 196608) {               // pu_perm[g][e][d']
    int i2 = i - 98304;
    int dp = i2 & 2047, e = (i2 >> 11) & 7, g = i2 >> 14;
    int h = dp >> 7, ul = dp & 127, d = (ul << 4) + h;
    pu_p[i2] = pu[(g << 14) + (e << 11) + d];
  } else if (i < 202752) {               // normalized codebooks, fp64
    int j = i - 196608;                  // j = g*1024 + k
    const float* row = cb + (j << 3);
    double ss = 0.0;
    #pragma unroll
    for (int e = 0; e < 8; ++e) { double x = (double)row[e]; ss += x * x; }
    double inv = 1.0 / fmax(sqrt(ss), 1e-12);
    #pragma unroll
    for (int e = 0; e < 8; ++e) cbn[(j << 3) + e] = (double)row[e] * inv;
  } else if (i < 202784) {               // zero the 32 loss accumulators
    loss_slots[i - 202752] = 0.0f;
  }
}

__global__ __launch_bounds__(256) void vq_main(
    const float* __restrict__ z, const float* __restrict__ cb,
    const float* __restrict__ pd_p, const float* __restrict__ pu_p,
    const double* __restrict__ cbn,
    float* __restrict__ out, float* __restrict__ loss_slots)
{
  __shared__ double part_d[16 * 128];   // 16 KB reduction buffer
  __shared__ double ze_d[TT * 8];
  __shared__ float  zq_s[TT * 8];
  __shared__ double wr_s[4][TT];
  __shared__ int    wr_k[4][TT];
  __shared__ float  lossv[TT];

  const int tid = threadIdx.x;
  const int tl  = tid & 127;    // index within e-half
  const int eh  = tid >> 7;     // which half of e (0: e0..3, 1: e4..7)
  const int tc  = blockIdx.x;   // 0..31 (chunk of TT=4 grouped frames)
  const int g   = blockIdx.y;   // 0..5
  const int b   = blockIdx.z;   // 0..15

  const float* zb = z + (size_t)b * (SEQ_ * C_);

  // ---------- phase 1: z_e partials, z direct-from-global, fp64 accum -------
  // thread owns dp pairs {i*256 + 2*tl, +1} for i in [0,8), e-range eh*4..+3.
  // pd read ONCE per block (each 16B half-row by exactly one thread).
  double acc[TT][4];
  #pragma unroll
  for (int t = 0; t < TT; ++t)
    #pragma unroll
    for (int j = 0; j < 4; ++j) acc[t][j] = 0.0;

  {
    const int hofs = tl >> 6;            // dp0>>7 parity
    const int ul2  = (tl & 63) << 1;
    const float* zbase = zb + (size_t)(tc * (TT * OV_)) * 192 + (g << 7) + ul2;
    const float* pdg = pd_p + ((g << 11) << 3) + (eh << 2);

    #pragma unroll 2
    for (int i = 0; i < 8; ++i) {
      const int h = (i << 1) + hofs;
      const float* zp = zbase + (size_t)h * (512 * 192);
      float2 zv[TT];
      #pragma unroll
      for (int t = 0; t < TT; ++t)
        zv[t] = *(const float2*)(zp + t * (OV_ * 192));
      const int dp0 = (i << 8) + (tl << 1);
      const float4 pa = *(const float4*)(pdg + (dp0 << 3));        // row dp0, e-half
      const float4 pb = *(const float4*)(pdg + ((dp0 + 1) << 3));  // row dp0+1, e-half
      #pragma unroll
      for (int t = 0; t < TT; ++t) {
        const double z0 = (double)zv[t].x, z1 = (double)zv[t].y;
        acc[t][0] = fma(z0, (double)pa.x, acc[t][0]);
        acc[t][1] = fma(z0, (double)pa.y, acc[t][1]);
        acc[t][2] = fma(z0, (double)pa.z, acc[t][2]);
        acc[t][3] = fma(z0, (double)pa.w, acc[t][3]);
        acc[t][0] = fma(z1, (double)pb.x, acc[t][0]);
        acc[t][1] = fma(z1, (double)pb.y, acc[t][1]);
        acc[t][2] = fma(z1, (double)pb.z, acc[t][2]);
        acc[t][3] = fma(z1, (double)pb.w, acc[t][3]);
      }
    }
  }

  // ---------- phase 1.5: block reduction, 2 rounds x 16 (t,e)-slots, fp64 ---
  // slot = tl2*8 + eh*4 + j  (tl2 = t within round pair); 128 partials/slot.
  #pragma unroll
  for (int r = 0; r < 2; ++r) {
    __syncthreads();
    #pragma unroll
    for (int tl2 = 0; tl2 < 2; ++tl2)
      #pragma unroll
      for (int j = 0; j < 4; ++j)
        part_d[(((tl2 << 3) + (eh << 2) + j) << 7) + tl] = acc[(r << 1) + tl2][j];
    __syncthreads();
    const int slot = tid >> 4, jj = tid & 15;
    double partial = 0.0;
    #pragma unroll
    for (int s = 0; s < 8; ++s)
      partial += part_d[(slot << 7) + (s << 4) + jj];
    partial += __shfl_down(partial, 8, 16);
    partial += __shfl_down(partial, 4, 16);
    partial += __shfl_down(partial, 2, 16);
    partial += __shfl_down(partial, 1, 16);
    if (jj == 0) ze_d[(r << 4) + slot] = partial;   // kk = t*8+e = r*16 + slot
  }
  __syncthreads();

  // ---------- phase 2: argmax over 1024 codes (fp64 sim, first-max tie-break)
  // codebook rows processed in pairs to halve live registers.
  double bs[TT]; int bk[TT];
  #pragma unroll
  for (int t = 0; t < TT; ++t) { bs[t] = -1.0e300; bk[t] = 0x7fffffff; }

  #pragma unroll
  for (int qp = 0; qp < 2; ++qp) {
    double cd2[2][8];
    #pragma unroll
    for (int qi = 0; qi < 2; ++qi) {
      const double* cr = cbn + (((g << 10) + (((qp << 1) + qi) << 8) + tid) << 3);
      #pragma unroll
      for (int e = 0; e < 8; ++e) cd2[qi][e] = cr[e];
    }
    #pragma unroll
    for (int t = 0; t < TT; ++t) {
      double s0 = 0.0, s1 = 0.0;
      #pragma unroll
      for (int e = 0; e < 8; ++e) {
        const double zr = ze_d[t * 8 + e];
        s0 = fma(zr, cd2[0][e], s0);
        s1 = fma(zr, cd2[1][e], s1);
      }
      const int k0 = ((qp << 1) << 8) + tid;        // ascending k within thread
      const int k1 = (((qp << 1) + 1) << 8) + tid;  // -> strict > keeps min k
      if (s0 > bs[t]) { bs[t] = s0; bk[t] = k0; }
      if (s1 > bs[t]) { bs[t] = s1; bk[t] = k1; }
    }
  }
  #pragma unroll
  for (int m = 32; m >= 1; m >>= 1) {
    #pragma unroll
    for (int t = 0; t < TT; ++t) {
      double os = __shfl_xor(bs[t], m);
      int    ok = __shfl_xor(bk[t], m);
      if (os > bs[t] || (os == bs[t] && ok < bk[t])) { bs[t] = os; bk[t] = ok; }
    }
  }
  const int wv4 = tid >> 6;
  if ((tid & 63) == 0) {
    #pragma unroll
    for (int t = 0; t < TT; ++t) { wr_s[wv4][t] = bs[t]; wr_k[wv4][t] = bk[t]; }
  }
  __syncthreads();
  if (tid < TT) {
    int t = tid;
    double s0 = wr_s[0][t]; int k0 = wr_k[0][t];
    #pragma unroll
    for (int w2 = 1; w2 < 4; ++w2) {
      double s1 = wr_s[w2][t]; int k1 = wr_k[w2][t];
      if (s1 > s0 || (s1 == s0 && k1 < k0)) { s0 = s1; k0 = k1; }
    }
    const float* crow = cb + (((g << 10) + k0) << 3);   // RAW codebook row
    double l = 0.0;
    #pragma unroll
    for (int e = 0; e < 8; ++e) {
      float qv = crow[e];
      zq_s[t * 8 + e] = qv;
      double dd = ze_d[t * 8 + e] - (double)qv;
      l = fma(dd, dd, l);
    }
    lossv[t] = (float)l;
  }
  __syncthreads();
  if (tid == 0) {
    float l = (lossv[0] + lossv[1] + lossv[2] + lossv[3]) * (1.0f / (T_ * D_ * G_));
    atomicAdd(loss_slots + b, l);        // commitment
    atomicAdd(loss_slots + 16 + b, l);   // codebook loss (numerically identical)
  }

  // ---------- phase 3: out = z_q @ proj_up, scatter-coalesced ----------
  float zqr[TT][8];
  #pragma unroll
  for (int t = 0; t < TT; ++t)
    #pragma unroll
    for (int e = 0; e < 8; ++e) zqr[t][e] = zq_s[t * 8 + e];

  #pragma unroll
  for (int j = 0; j < 8; ++j) {
    int dp = j * 256 + tid;
    int h = dp >> 7, ul = dp & 127;
    int u = (g << 7) + ul;
    int o = (u * 683) >> 17;
    int c = u - o * 192;
    float pv[8];
    #pragma unroll
    for (int e = 0; e < 8; ++e) pv[e] = pu_p[(g << 14) + (e << 11) + dp];
    size_t base = ((size_t)(b * SEQ_) + h * 512 + tc * (TT * OV_) + o) * 192 + c;
    #pragma unroll
    for (int t = 0; t < TT; ++t) {
      float v = 0.f;
      #pragma unroll
      for (int e = 0; e < 8; ++e) v = fmaf(zqr[t][e], pv[e], v);
      out[base + (size_t)(t * OV_ * 192)] = v;
    }
  }
}

extern "C" void kernel_launch(void* const* d_in, const int* in_sizes, int n_in,
                              void* d_out, int out_size, void* d_ws, size_t ws_size,
                              hipStream_t stream)
{
  const float* z  = (const float*)d_in[0];   // (B, SEQ, C)
  const float* pd = (const float*)d_in[1];   // (G, DG, D)
  const float* pu = (const float*)d_in[2];   // (G, D, DG)
  const float* cb = (const float*)d_in[3];   // (G, K, D)
  float* out = (float*)d_out;
  float* loss_slots = out + OUT_ELEMS;       // 16 commitment + 16 codebook

  float*  pd_p = (float*)d_ws;
  float*  pu_p = pd_p + 98304;
  double* cbn  = (double*)(pu_p + 98304);

  vq_prep<<<793, 256, 0, stream>>>(pd, pu, cb, pd_p, pu_p, cbn, loss_slots);
  dim3 grid(T_ / TT, G_, B_);
  vq_main<<<grid, 256, 0, stream>>>(z, cb, pd_p, pu_p, cbn, out, loss_slots);
}